// Round 11
// baseline (3090.898 us; speedup 1.0000x reference)
//
#include <hip/hip_runtime.h>
#include <hip/hip_bf16.h>

#define NB    32768
#define NIN   1024
#define NHID  2048
#define NLAT  64
#define NEMB  4096
#define BETA  0.25f

#define FLTMAX 3.402823466e+38f

// ---- output layout (FLOAT32 elements) ----
#define XR_OFF   0
#define ZE_OFF   33554432
#define ZQ_OFF   35651584
#define IDX_OFF  37748736
#define LOSS_OFF 37781504

// ---- ws layout (bytes) ----
#define PART_WS_F   0          // 256 f32 loss partials
#define W1T_WS_B    4096
#define W2T_WS_B    266240

typedef short v8s __attribute__((ext_vector_type(8)));
typedef float v4f __attribute__((ext_vector_type(4)));

static __device__ __forceinline__ unsigned short f2bf(float f) {
    union { __hip_bfloat16 h; unsigned short u; } v;
    v.h = __float2bfloat16(f);
    return v.u;
}

static __device__ __forceinline__ void fma4(float4& acc, float s, const float4& wv) {
    acc.x += s * wv.x; acc.y += s * wv.y; acc.z += s * wv.z; acc.w += s * wv.w;
}

// ---------------- prep: transpose+convert decoder weights to bf16 ----------------
__global__ void prep_w1t(const float* __restrict__ dw1, unsigned short* __restrict__ w1t) {
    int idx = blockIdx.x * 256 + threadIdx.x;
    int l = idx >> 11, h = idx & 2047;
    w1t[h * 64 + l] = f2bf(dw1[l * 2048 + h]);
}
__global__ void prep_w2t(const float* __restrict__ dw2, unsigned short* __restrict__ w2t) {
    int idx = blockIdx.x * 256 + threadIdx.x;
    int k = idx >> 10, c = idx & 1023;
    w2t[(size_t)c * 2048 + k] = f2bf(dw2[(size_t)k * 1024 + c]);
}

// ---------------- fused encoder + VQ (fp32, exact indices) ----------------
// 512 threads, 128 rows/block. rg=t>>5 (0..15): rows rg+16i (i 0..7);
// cg=t&31 (0..31): GEMM1 cols cg*8..+7 of the 256-wide jc chunk.
// GEMM1: NO LDS, NO barriers — x and w1 streamed from global (L1/L2-cached).
// FMA order identical to the R10 passing kernel -> bitwise-same z_e/indices.
__global__ __launch_bounds__(512)
void encvq_kernel(const float* __restrict__ x,  const float* __restrict__ w1,
                  const float* __restrict__ b1, const float* __restrict__ w2,
                  const float* __restrict__ b2, const float* __restrict__ cb,
                  float* __restrict__ out, float* __restrict__ partials) {
    float* ze_out  = out + ZE_OFF;
    float* zq_out  = out + ZQ_OFF;
    float* idx_out = out + IDX_OFF;

    __shared__ __align__(16) float hs[128 * 36];     // 18.4 KB
    __shared__ __align__(16) float w2s[32 * 68];     //  8.7 KB
    __shared__ __align__(16) float zs[128 * 68];     // 34.8 KB
    __shared__ __align__(16) float cbs[128 * 68];    // 34.8 KB
    __shared__ float rbestf[128 * 33];               // 16.9 KB (dedicated, no alias)
    __shared__ int   ridxi[128 * 33];                // 16.9 KB
    __shared__ float zsq[128];
    __shared__ float eqs[128];
    __shared__ float lred[128];

    const int t = threadIdx.x;
    const int rg = t >> 5, cg = t & 31;
    const int brow = blockIdx.x * 128;

    // ---------------- phase 1: encoder ----------------
    float2 zacc[8];
#pragma unroll
    for (int i = 0; i < 8; i++) zacc[i] = make_float2(0.f, 0.f);

    // per-row x base pointers (constant across jc)
    const float* xrow[8];
#pragma unroll
    for (int i = 0; i < 8; i++) xrow[i] = &x[(size_t)(brow + rg + 16 * i) * NIN];

    for (int jc = 0; jc < NHID; jc += 256) {
        float4 hacc[8][2];
#pragma unroll
        for (int i = 0; i < 8; i++) {
            hacc[i][0] = make_float4(0.f, 0.f, 0.f, 0.f);
            hacc[i][1] = make_float4(0.f, 0.f, 0.f, 0.f);
        }
        const float* wb = &w1[jc + cg * 8];

#pragma unroll 2
        for (int k4 = 0; k4 < NIN; k4 += 4) {
            float4 av[8];
#pragma unroll
            for (int i = 0; i < 8; i++)
                av[i] = *reinterpret_cast<const float4*>(xrow[i] + k4);
            float4 wv0[4], wv1[4];
#pragma unroll
            for (int kk = 0; kk < 4; kk++) {
                const float* wr = wb + (size_t)(k4 + kk) * NHID;
                wv0[kk] = *reinterpret_cast<const float4*>(wr);
                wv1[kk] = *reinterpret_cast<const float4*>(wr + 4);
            }
#pragma unroll
            for (int kk = 0; kk < 4; kk++) {
#pragma unroll
                for (int i = 0; i < 8; i++) {
                    float a = (kk == 0) ? av[i].x : (kk == 1) ? av[i].y : (kk == 2) ? av[i].z : av[i].w;
                    fma4(hacc[i][0], a, wv0[kk]);
                    fma4(hacc[i][1], a, wv1[kk]);
                }
            }
        }

        // GEMM2 over 8 sub-chunks of 32 hidden cols (same as R10, bitwise)
        for (int cs = 0; cs < 8; cs++) {
            __syncthreads();   // prev reads of hs/w2s done
            if ((cg >> 2) == cs) {                          // owners write h chunk
                float4 b1a = *reinterpret_cast<const float4*>(&b1[jc + cg * 8]);
                float4 b1b = *reinterpret_cast<const float4*>(&b1[jc + cg * 8 + 4]);
#pragma unroll
                for (int i = 0; i < 8; i++) {
                    float4 h0, h1;
                    h0.x = fmaxf(hacc[i][0].x + b1a.x, 0.f);
                    h0.y = fmaxf(hacc[i][0].y + b1a.y, 0.f);
                    h0.z = fmaxf(hacc[i][0].z + b1a.z, 0.f);
                    h0.w = fmaxf(hacc[i][0].w + b1a.w, 0.f);
                    h1.x = fmaxf(hacc[i][1].x + b1b.x, 0.f);
                    h1.y = fmaxf(hacc[i][1].y + b1b.y, 0.f);
                    h1.z = fmaxf(hacc[i][1].z + b1b.z, 0.f);
                    h1.w = fmaxf(hacc[i][1].w + b1b.w, 0.f);
                    *reinterpret_cast<float4*>(&hs[(rg + 16 * i) * 36 + (cg & 3) * 8]) = h0;
                    *reinterpret_cast<float4*>(&hs[(rg + 16 * i) * 36 + (cg & 3) * 8 + 4]) = h1;
                }
            }
            // stage w2s [32][64] : 512 float4, 1/thread
            {
                int r = t >> 4, c4 = (t & 15) * 4;
                *reinterpret_cast<float4*>(&w2s[r * 68 + c4]) =
                    *reinterpret_cast<const float4*>(&w2[(size_t)(jc + 32 * cs + r) * NLAT + c4]);
            }
            __syncthreads();
#pragma unroll 4
            for (int k = 0; k < 32; k++) {
                float2 wv = *reinterpret_cast<float2*>(&w2s[k * 68 + cg * 2]);
#pragma unroll
                for (int i = 0; i < 8; i++) {
                    float hv = hs[(rg + 16 * i) * 36 + k];
                    zacc[i].x += hv * wv.x;
                    zacc[i].y += hv * wv.y;
                }
            }
        }
    }

    // finalize z: bias, write zs + ze_out
    __syncthreads();
    {
        float2 b2v = *reinterpret_cast<const float2*>(&b2[cg * 2]);
#pragma unroll
        for (int i = 0; i < 8; i++) {
            int row = brow + rg + 16 * i;
            float2 z = make_float2(zacc[i].x + b2v.x, zacc[i].y + b2v.y);
            *reinterpret_cast<float2*>(&zs[(rg + 16 * i) * 68 + cg * 2]) = z;
            *reinterpret_cast<float2*>(&ze_out[(size_t)row * NLAT + cg * 2]) = z;
        }
    }
    __syncthreads();

    // ---------------- phase 2: VQ (same as R10) ----------------
    if (t < 128) {
        float s = 0.f;
#pragma unroll 16
        for (int d = 0; d < 64; d++) { float v = zs[t * 68 + d]; s += v * v; }
        zsq[t] = s;
    }
    __syncthreads();
    float zr[8];
#pragma unroll
    for (int i = 0; i < 8; i++) zr[i] = zsq[rg + 16 * i];

    float best[8]; int bidx[8];
#pragma unroll
    for (int i = 0; i < 8; i++) { best[i] = FLTMAX; bidx[i] = 0; }

    for (int cc = 0; cc < NEMB; cc += 128) {
        __syncthreads();
#pragma unroll
        for (int jj = 0; jj < 4; jj++) {                  // stage codebook [128][64]
            int id = t + 512 * jj;
            int r = id >> 4, c4 = (id & 15) * 4;
            *reinterpret_cast<float4*>(&cbs[r * 68 + c4]) =
                *reinterpret_cast<const float4*>(&cb[(size_t)(cc + r) * NLAT + c4]);
        }
        __syncthreads();
        if (t < 128) {                                    // in-LDS codebook norms
            float s = 0.f;
#pragma unroll 16
            for (int d = 0; d < 64; d++) { float v = cbs[t * 68 + d]; s += v * v; }
            eqs[t] = s;
        }
        __syncthreads();
        float dot[8][4];
#pragma unroll
        for (int i = 0; i < 8; i++)
#pragma unroll
            for (int j = 0; j < 4; j++) dot[i][j] = 0.f;
#pragma unroll 2
        for (int d4 = 0; d4 < 64; d4 += 4) {
            float4 zv[8];
#pragma unroll
            for (int i = 0; i < 8; i++)
                zv[i] = *reinterpret_cast<float4*>(&zs[(rg + 16 * i) * 68 + d4]);
#pragma unroll
            for (int j = 0; j < 4; j++) {
                float4 cv = *reinterpret_cast<float4*>(&cbs[(cg + 32 * j) * 68 + d4]);
#pragma unroll
                for (int i = 0; i < 8; i++) {
                    dot[i][j] += zv[i].x*cv.x + zv[i].y*cv.y + zv[i].z*cv.z + zv[i].w*cv.w;
                }
            }
        }
#pragma unroll
        for (int j = 0; j < 4; j++) {
            int cl = cg + 32 * j;                         // ascending per thread
            float eq = eqs[cl];
#pragma unroll
            for (int i = 0; i < 8; i++) {
                float d2 = (zr[i] - 2.f * dot[i][j]) + eq;
                if (d2 < best[i]) { best[i] = d2; bidx[i] = cc + cl; }
            }
        }
    }
    __syncthreads();   // keep (harmless; rbest/ridx are dedicated now)
    // LDS argmin reduce across the 32 lane-columns of each row
#pragma unroll
    for (int i = 0; i < 8; i++) {
        rbestf[(rg + 16 * i) * 33 + cg] = best[i];
        ridxi [(rg + 16 * i) * 33 + cg] = bidx[i];
    }
    __syncthreads();
    if (t < 128) {
        float b = rbestf[t * 33]; int bi = ridxi[t * 33];
        for (int l = 1; l < 32; l++) {
            float ob = rbestf[t * 33 + l]; int oi = ridxi[t * 33 + l];
            if (ob < b || (ob == b && oi < bi)) { b = ob; bi = oi; }
        }
        int c = bi & (NEMB - 1);
        int row = brow + t;
        idx_out[row] = (float)c;
        float s = 0.f;
#pragma unroll
        for (int d4 = 0; d4 < 64; d4 += 4) {
            float4 q = *reinterpret_cast<const float4*>(&cb[(size_t)c * NLAT + d4]);
            float z0 = zs[t * 68 + d4 + 0], z1 = zs[t * 68 + d4 + 1];
            float z2 = zs[t * 68 + d4 + 2], z3 = zs[t * 68 + d4 + 3];
            float dx = q.x - z0, dy = q.y - z1, dz = q.z - z2, dw = q.w - z3;
            s += dx*dx + dy*dy + dz*dz + dw*dw;
            *reinterpret_cast<float4*>(&zq_out[(size_t)row * NLAT + d4]) = q;
        }
        lred[t] = s;
    }
    __syncthreads();
    if (t == 0) {
        float s = 0.f;
        for (int q = 0; q < 128; q++) s += lred[q];
        partials[blockIdx.x] = s;
    }
}

// ---------------- loss ----------------
__global__ void loss_kernel(const float* __restrict__ partials, float* __restrict__ out_loss) {
    if (threadIdx.x == 0 && blockIdx.x == 0) {
        float s = 0.f;
        for (int i = 0; i < 256; i++) s += partials[i];
        *out_loss = (1.f + BETA) * s / (float)((size_t)NB * NLAT);
    }
}

// ---------------- MFMA decoder (unchanged from R8/R10) ----------------
__global__ __launch_bounds__(256)
void dec_kernel(const float* __restrict__ out_base,
                const unsigned short* __restrict__ w1t,
                const unsigned short* __restrict__ w2t,
                const float* __restrict__ b1, const float* __restrict__ b2,
                float* __restrict__ xr) {
    const float* zq_in = out_base + ZQ_OFF;

    __shared__ __align__(16) unsigned short zqb[64 * 72];
    __shared__ __align__(16) unsigned short w1b[64 * 72];
    __shared__ __align__(16) unsigned short hdb[64 * 72];
    __shared__ __align__(16) unsigned short w2b[256 * 72];

    const int t = threadIdx.x;
    const int w = t >> 6, lane = t & 63, lo = lane & 15, hi = lane >> 4;
    const int rb = blockIdx.x >> 2, cbk = blockIdx.x & 3;
    const int brow = rb * 64, cbase = cbk * 256;

    {
        int row = t & 63, m = t >> 6;
        const float* src = &zq_in[(size_t)(brow + row) * NLAT + m * 16];
        unsigned int us[8];
#pragma unroll
        for (int j = 0; j < 4; j++) {
            float4 v = *reinterpret_cast<const float4*>(src + 4 * j);
            us[2*j]   = (unsigned int)f2bf(v.x) | ((unsigned int)f2bf(v.y) << 16);
            us[2*j+1] = (unsigned int)f2bf(v.z) | ((unsigned int)f2bf(v.w) << 16);
        }
        uint4 p0 = make_uint4(us[0], us[1], us[2], us[3]);
        uint4 p1 = make_uint4(us[4], us[5], us[6], us[7]);
        *reinterpret_cast<uint4*>(&zqb[row * 72 + m * 16 + 0]) = p0;
        *reinterpret_cast<uint4*>(&zqb[row * 72 + m * 16 + 8]) = p1;
    }

    v4f facc[4][4];
#pragma unroll
    for (int i = 0; i < 4; i++)
#pragma unroll
        for (int j = 0; j < 4; j++) facc[i][j] = (v4f){0.f, 0.f, 0.f, 0.f};

    for (int hc = 0; hc < NHID; hc += 64) {
        __syncthreads();
        {
            int cl = t & 63, mm = (t >> 6) * 2;
#pragma unroll
            for (int j = 0; j < 2; j++) {
                uint4 v = *reinterpret_cast<const uint4*>(&w1t[(size_t)(hc + cl) * 64 + (mm + j) * 8]);
                *reinterpret_cast<uint4*>(&w1b[cl * 72 + (mm + j) * 8]) = v;
            }
        }
        {
            const unsigned short* src = &w2t[(size_t)(cbase + t) * 2048 + hc];
#pragma unroll
            for (int j = 0; j < 8; j++) {
                uint4 v = *reinterpret_cast<const uint4*>(src + j * 8);
                *reinterpret_cast<uint4*>(&w2b[t * 72 + j * 8]) = v;
            }
        }
        __syncthreads();

        v8s a0 = *reinterpret_cast<const v8s*>(&zqb[(16 * w + lo) * 72 +  0 + hi * 8]);
        v8s a1 = *reinterpret_cast<const v8s*>(&zqb[(16 * w + lo) * 72 + 32 + hi * 8]);
#pragma unroll
        for (int ct = 0; ct < 4; ct++) {
            v8s bb0 = *reinterpret_cast<const v8s*>(&w1b[(16 * ct + lo) * 72 +  0 + hi * 8]);
            v8s bb1 = *reinterpret_cast<const v8s*>(&w1b[(16 * ct + lo) * 72 + 32 + hi * 8]);
            v4f acc = (v4f){0.f, 0.f, 0.f, 0.f};
            acc = __builtin_amdgcn_mfma_f32_16x16x32_bf16(a0, bb0, acc, 0, 0, 0);
            acc = __builtin_amdgcn_mfma_f32_16x16x32_bf16(a1, bb1, acc, 0, 0, 0);
            float bias = b1[hc + 16 * ct + lo];
#pragma unroll
            for (int r = 0; r < 4; r++) {
                float hv = fmaxf(acc[r] + bias, 0.f);
                hdb[(16 * w + 4 * hi + r) * 72 + 16 * ct + lo] = f2bf(hv);
            }
        }
        __syncthreads();

#pragma unroll
        for (int kk = 0; kk < 2; kk++) {
            v8s af[4];
#pragma unroll
            for (int rt = 0; rt < 4; rt++)
                af[rt] = *reinterpret_cast<const v8s*>(&hdb[(16 * rt + lo) * 72 + kk * 32 + hi * 8]);
#pragma unroll
            for (int ctl = 0; ctl < 4; ctl++) {
                v8s bf_ = *reinterpret_cast<const v8s*>(&w2b[(64 * w + 16 * ctl + lo) * 72 + kk * 32 + hi * 8]);
#pragma unroll
                for (int rt = 0; rt < 4; rt++)
                    facc[rt][ctl] = __builtin_amdgcn_mfma_f32_16x16x32_bf16(af[rt], bf_, facc[rt][ctl], 0, 0, 0);
            }
        }
    }

#pragma unroll
    for (int ctl = 0; ctl < 4; ctl++) {
        int col = cbase + 64 * w + 16 * ctl + lo;
        float bias = b2[col];
#pragma unroll
        for (int rt = 0; rt < 4; rt++) {
#pragma unroll
            for (int r = 0; r < 4; r++) {
                int row = brow + 16 * rt + 4 * hi + r;
                xr[(size_t)row * NIN + col] = facc[rt][ctl][r] + bias;
            }
        }
    }
}

extern "C" void kernel_launch(void* const* d_in, const int* in_sizes, int n_in,
                              void* d_out, int out_size, void* d_ws, size_t ws_size,
                              hipStream_t stream) {
    (void)in_sizes; (void)n_in; (void)out_size; (void)ws_size;
    const float* x   = (const float*)d_in[0];
    const float* ew1 = (const float*)d_in[1];
    const float* eb1 = (const float*)d_in[2];
    const float* ew2 = (const float*)d_in[3];
    const float* eb2 = (const float*)d_in[4];
    const float* cb  = (const float*)d_in[5];
    const float* dw1 = (const float*)d_in[6];
    const float* db1 = (const float*)d_in[7];
    const float* dw2 = (const float*)d_in[8];
    const float* db2 = (const float*)d_in[9];

    float* out  = (float*)d_out;
    float* part = (float*)d_ws + PART_WS_F;
    unsigned short* w1t = (unsigned short*)((char*)d_ws + W1T_WS_B);
    unsigned short* w2t = (unsigned short*)((char*)d_ws + W2T_WS_B);

    prep_w1t<<<512, 256, 0, stream>>>(dw1, w1t);
    prep_w2t<<<8192, 256, 0, stream>>>(dw2, w2t);
    encvq_kernel<<<NB / 128, 512, 0, stream>>>(x, ew1, eb1, ew2, eb2, cb, out, part);
    loss_kernel<<<1, 64, 0, stream>>>(part, out + LOSS_OFF);
    dec_kernel<<<(NB / 64) * 4, 256, 0, stream>>>(out, w1t, w2t, db1, db2, out + XR_OFF);
}